// Round 4
// baseline (28971.466 us; speedup 1.0000x reference)
//
#include <hip/hip_runtime.h>
#include <hip/hip_fp16.h>
#include <hip/hip_cooperative_groups.h>

namespace cg = cooperative_groups;

constexpr int B_ = 128, T_ = 1024, D_ = 512, U_ = 512;
constexpr int NBLK = 256, NTHR = 1024;
constexpr int G4 = 4 * U_;   // 2048 gate columns
constexpr int NGRP = 16, GRPSZ = 16;   // hierarchical barrier
constexpr int NRED = 16;               // reducer blocks (8 b's each)

__device__ __forceinline__ float sigm(float v) { return 1.0f / (1.0f + expf(-v)); }

#define AGENT_LD(p)    __hip_atomic_load((p), __ATOMIC_RELAXED, __HIP_MEMORY_SCOPE_AGENT)
#define AGENT_ST(p, v) __hip_atomic_store((p), (v), __ATOMIC_RELAXED, __HIP_MEMORY_SCOPE_AGENT)

template <typename ZT> __device__ __forceinline__ ZT    to_zt(float v);
template <> __device__ __forceinline__ float  to_zt<float>(float v)  { return v; }
template <> __device__ __forceinline__ __half to_zt<__half>(float v) { return __float2half(v); }
__device__ __forceinline__ float from_zt(float v)  { return v; }
__device__ __forceinline__ float from_zt(__half v) { return __half2float(v); }

// ---------------- x[b][t][k] -> xT[t][k][b] ----------------------------------------
__global__ __launch_bounds__(256) void transpose_x(const float* __restrict__ x,
                                                   float* __restrict__ xT)
{
    __shared__ float tile[32][33];
    const int tileId = blockIdx.x;
    const int bt = tileId & 3;
    const int kt = (tileId >> 2) & 15;
    const int t  = tileId >> 6;
    const int tx = threadIdx.x & 31;
    const int ty = threadIdx.x >> 5;
    #pragma unroll
    for (int r = 0; r < 4; ++r) {
        const int b = bt * 32 + ty + r * 8;
        const int k = kt * 32 + tx;
        tile[ty + r * 8][tx] = x[(size_t)b * (T_ * D_) + (size_t)t * D_ + k];
    }
    __syncthreads();
    #pragma unroll
    for (int r = 0; r < 4; ++r) {
        const int k = kt * 32 + ty + r * 8;
        const int b = bt * 32 + tx;
        xT[((size_t)t * D_ + k) * B_ + b] = tile[tx][ty + r * 8];
    }
}

// ---------------- pack W: Wpk[blk][k 0..1023][c 0..7] ------------------------------
__global__ __launch_bounds__(1024) void pack_w(const float* __restrict__ wk,
                                               const float* __restrict__ wr,
                                               float* __restrict__ Wpk)
{
    const size_t idx = (size_t)blockIdx.x * 1024 + threadIdx.x;
    const int    c   = (int)(idx & 7);
    const size_t k   = (idx >> 3) & 1023;
    const int    blk = (int)(idx >> 13);
    const int    col = ((c >> 1) << 9) + blk * 2 + (c & 1);
    Wpk[idx] = (k < 512) ? wk[k * G4 + col] : wr[(k - 512) * G4 + col];
}

// ---------------- zx[t][c][b] = bias + x_t @ Wk ------------------------------------
template <typename ZT>
__global__ __launch_bounds__(NTHR, 4) void zx_gemm(
    const float* __restrict__ xT, const float* __restrict__ Wpk,
    const float* __restrict__ bias, ZT* __restrict__ zx)
{
    __shared__ float parts[8][128][9];
    __shared__ float bias_l[8];
    const int tid = threadIdx.x, blk = blockIdx.x, u0 = blk * 2;
    if (tid < 8) bias_l[tid] = bias[(tid >> 1) * U_ + u0 + (tid & 1)];
    const int b = tid & 127, ksub = tid >> 7;
    const int ksub_u = __builtin_amdgcn_readfirstlane(ksub);
    const float* __restrict__ wp = Wpk + ((size_t)blk * 1024 + (size_t)ksub_u * 64) * 8;
    __syncthreads();

    for (int t = 0; t < T_; ++t) {
        const float* __restrict__ xp = xT + ((size_t)t * D_ + ksub * 64) * B_ + b;
        float acc[8] = {0.f,0.f,0.f,0.f,0.f,0.f,0.f,0.f};
        #pragma unroll 2
        for (int kq = 0; kq < 16; ++kq) {
            const float v0 = xp[(kq * 4 + 0) * B_];
            const float v1 = xp[(kq * 4 + 1) * B_];
            const float v2 = xp[(kq * 4 + 2) * B_];
            const float v3 = xp[(kq * 4 + 3) * B_];
            const float* __restrict__ w = wp + kq * 32;
            #pragma unroll
            for (int c = 0; c < 8; ++c)
                acc[c] += v0 * w[c] + v1 * w[8 + c] + v2 * w[16 + c] + v3 * w[24 + c];
        }
        #pragma unroll
        for (int c = 0; c < 8; ++c) parts[ksub][b][c] = acc[c];
        __syncthreads();
        {
            const int c = tid >> 7, bb = tid & 127;
            float s = bias_l[c];
            #pragma unroll
            for (int ks = 0; ks < 8; ++ks) s += parts[ks][bb][c];
            zx[((size_t)t * G4 + (c >> 1) * U_ + u0 + (c & 1)) * B_ + bb] = to_zt<ZT>(s);
        }
        __syncthreads();
    }
}

// ---------------- main recurrent loop ----------------------------------------------
// ctrl layout (uint idx): [0..255] grp counters (stride 16), [256] root,
// [272] dready, byte 1152+: float delta_g[2][128].
template <typename ZT>
__global__ __launch_bounds__(NTHR, 4) void skiplstm_loop(
    const ZT* __restrict__ zx, const float* __restrict__ Wpk,
    const float* __restrict__ dk, const float* __restrict__ dbp,
    float* __restrict__ out, float* __restrict__ hbuf,
    float* __restrict__ pd, unsigned* __restrict__ ctrl)
{
    __shared__ float parts[8][128][9];
    __shared__ float zxl[8][128];
    __shared__ float red[8][132];
    __shared__ float c_state[128][2];
    __shared__ float h_state[128][2];
    __shared__ float ut_lds[128];
    __shared__ float dk_l[4];
    __shared__ float db_l;

    const int tid = threadIdx.x;
    const int blk = blockIdx.x;
    const int u0  = blk * 2;

    unsigned* __restrict__ bar_grp  = ctrl;                 // [g*16]
    unsigned* __restrict__ bar_root = ctrl + 256;
    unsigned* __restrict__ dready   = ctrl + 272;
    float*    __restrict__ delta_g  = (float*)(ctrl + 288); // [2][128]

    if (tid < 2) { dk_l[tid] = dk[u0 + tid]; dk_l[2 + tid] = dk[U_ + u0 + tid]; }
    if (tid == 0) db_l = dbp[0];
    if (tid < 128) {
        ut_lds[tid] = 1.0f;
        c_state[tid][0] = 0.f; c_state[tid][1] = 0.f;
        h_state[tid][0] = 0.f; h_state[tid][1] = 0.f;
    }
    __syncthreads();

    const int b    = tid & 127;
    const int ksub = tid >> 7;
    const int ksub_u = __builtin_amdgcn_readfirstlane(ksub);
    const float* __restrict__ wp = Wpk + ((size_t)blk * 1024 + 512 + (size_t)ksub_u * 64) * 8;
    const int g = blk >> 4;   // barrier group

    #pragma unroll 1
    for (int t = 0; t < T_; ++t) {
        const float* __restrict__ hcur = hbuf + (t & 1) * (U_ * B_);
        float* __restrict__ hnxt = hbuf + ((t + 1) & 1) * (U_ * B_);

        // ---- [A] zx prefetch (issued first; latency hides under phase 1a) ----
        const ZT zreg = zx[((size_t)t * G4 + (ksub >> 1) * U_ + u0 + (ksub & 1)) * B_ + b];

        // ---- [B] phase 1a: stage all 64 h values, then FMA ----
        const float* __restrict__ hp = hcur + (size_t)(ksub * 64) * B_ + b;
        float hv[64];
        #pragma unroll
        for (int i = 0; i < 64; ++i) hv[i] = AGENT_LD(hp + i * B_);

        float acc[8] = {0.f,0.f,0.f,0.f,0.f,0.f,0.f,0.f};
        #pragma unroll
        for (int kq = 0; kq < 16; ++kq) {
            const float* __restrict__ w = wp + kq * 32;   // wave-uniform -> s_load
            #pragma unroll
            for (int c = 0; c < 8; ++c)
                acc[c] += hv[4*kq+0] * w[c]      + hv[4*kq+1] * w[8 + c]
                        + hv[4*kq+2] * w[16 + c] + hv[4*kq+3] * w[24 + c];
        }
        #pragma unroll
        for (int c = 0; c < 8; ++c) parts[ksub][b][c] = acc[c];
        zxl[ksub][b] = from_zt(zreg);
        __syncthreads();   // [C]

        // ---- [F] gates, blend, output, dense partial (waves 0-3) ----
        if (tid < 256) {
            const int bb = tid >> 1, j = tid & 1;
            float ut, ug;
            if (t == 0) { ut = 1.0f; ug = 1.0f; }
            else {
                const unsigned tgt_d = (unsigned)(NRED * t);
                while (AGENT_LD(dready) < tgt_d) __builtin_amdgcn_s_sleep(1);
                const float dlt = AGENT_LD(delta_g + ((t - 1) & 1) * 128 + bb);
                const float utp = ut_lds[bb];
                const float ugp = rintf(utp);
                ut = ugp * dlt + (1.f - ugp) * (utp + fminf(dlt, 1.f - utp));
                ug = rintf(ut);
            }
            float z[4];
            #pragma unroll
            for (int gg4 = 0; gg4 < 4; ++gg4) {
                float s = zxl[gg4 * 2 + j][bb];
                #pragma unroll
                for (int ks = 0; ks < 8; ++ks) s += parts[ks][bb][gg4 * 2 + j];
                z[gg4] = s;
            }
            const float c_old = c_state[bb][j];
            const float si = sigm(z[0]);
            const float sf = sigm(z[1]);
            const float gt = tanhf(z[2]);
            const float so = sigm(z[3]);
            const float c_n = sf * c_old + si * gt;
            const float h_n = so * tanhf(c_n);
            const float h_old = h_state[bb][j];
            const float hbv = ug * h_old + (1.f - ug) * h_n;
            const float cbv = ug * c_old + (1.f - ug) * c_n;
            out[(size_t)bb * (T_ * U_) + (size_t)t * U_ + u0 + j] = h_n;
            AGENT_ST(hnxt + (size_t)(u0 + j) * B_ + bb, hbv);
            c_state[bb][j] = cbv;
            h_state[bb][j] = hbv;
            float p = hbv * dk_l[j] + cbv * dk_l[2 + j];
            p += __shfl_xor(p, 1);
            if (j == 0) {
                AGENT_ST(pd + (t & 1) * (NBLK * B_) + blk * B_ + bb, p);
                ut_lds[bb] = ut;
            }
        }
        __syncthreads();   // [G] drain stores before arrive

        // ---- [H] hierarchical grid barrier ----
        if (tid == 0) {
            const unsigned old = __hip_atomic_fetch_add(bar_grp + g * 16, 1u,
                                    __ATOMIC_RELEASE, __HIP_MEMORY_SCOPE_AGENT);
            if (old + 1u == (unsigned)(GRPSZ * (t + 1)))
                __hip_atomic_fetch_add(bar_root, 1u,
                                    __ATOMIC_RELEASE, __HIP_MEMORY_SCOPE_AGENT);
            const unsigned tgt = (unsigned)(NGRP * (t + 1));
            while (__hip_atomic_load(bar_root, __ATOMIC_RELAXED, __HIP_MEMORY_SCOPE_AGENT) < tgt)
                __builtin_amdgcn_s_sleep(1);
        }
        __syncthreads();

        // ---- [I] reducers: pd -> delta (overlaps other blocks' next phase 1a) ----
        if (blk < NRED && t < T_ - 1) {
            const int b8 = tid & 7, i = tid >> 3;          // i in 0..127
            const int bg = blk * 8 + b8;
            const float* __restrict__ pdt = pd + (t & 1) * (NBLK * B_);
            red[b8][i] = AGENT_LD(pdt + (size_t)(i * 2 + 0) * B_ + bg)
                       + AGENT_LD(pdt + (size_t)(i * 2 + 1) * B_ + bg);
            __syncthreads();
            if (tid < 8) {
                float ss = 0.f;
                #pragma unroll 4
                for (int i2 = 0; i2 < 128; ++i2) ss += red[tid][i2];
                AGENT_ST(delta_g + (t & 1) * 128 + blk * 8 + tid, sigm(ss + db_l));
            }
            __syncthreads();
            if (tid == 0)
                __hip_atomic_fetch_add(dready, 1u,
                                    __ATOMIC_RELEASE, __HIP_MEMORY_SCOPE_AGENT);
        }
    }
}

// ---------------- R2 fallback (ws too small) ---------------------------------------
__global__ __launch_bounds__(NTHR, 4) void skiplstm_kernel_T(
    const float* __restrict__ xT, const float* __restrict__ wk,
    const float* __restrict__ wr, const float* __restrict__ bias,
    const float* __restrict__ dk, const float* __restrict__ dbp,
    float* __restrict__ out, float* __restrict__ hbuf, float* __restrict__ pd)
{
    __shared__ __align__(16) float Wlds[8][1024];
    __shared__ float parts[8][128][9];
    __shared__ float c_state[128][2];
    __shared__ float ut_lds[128];
    __shared__ float bias_l[8];
    __shared__ float dk_l[4];
    __shared__ float db_l;

    const int tid = threadIdx.x;
    const int u0 = blockIdx.x * 2;

    #pragma unroll
    for (int c = 0; c < 8; ++c) {
        const int g = c >> 1, j = c & 1;
        const int gcol = g * U_ + u0 + j;
        Wlds[c][tid] = (tid < D_) ? wk[(size_t)tid * G4 + gcol]
                                  : wr[(size_t)(tid - D_) * G4 + gcol];
    }
    if (tid < 8)  bias_l[tid] = bias[(tid >> 1) * U_ + u0 + (tid & 1)];
    if (tid < 2) { dk_l[tid] = dk[u0 + tid]; dk_l[2 + tid] = dk[U_ + u0 + tid]; }
    if (tid == 0) db_l = dbp[0];
    if (tid < 128) { ut_lds[tid] = 1.0f; c_state[tid][0] = 0.0f; c_state[tid][1] = 0.0f; }
    if (tid < 512) hbuf[blockIdx.x * 512 + tid] = 0.0f;

    cg::grid_group grid = cg::this_grid();
    __syncthreads();
    grid.sync();

    const int b    = tid & 127;
    const int ksub = tid >> 7;

    #pragma unroll 1
    for (int t = 0; t < T_; ++t) {
        const float* __restrict__ hcurT = hbuf + (t & 1) * (U_ * B_);
        float* __restrict__ hnxtT = hbuf + ((t + 1) & 1) * (U_ * B_);

        const float* __restrict__ src = (ksub < 4)
            ? (xT + ((size_t)t * D_ + ksub * 128) * B_ + b)
            : (hcurT + (size_t)(ksub - 4) * 128 * B_ + b);

        float acc[8] = {0.f,0.f,0.f,0.f,0.f,0.f,0.f,0.f};
        #pragma unroll 2
        for (int kq = 0; kq < 32; ++kq) {
            const float v0 = src[(kq * 4 + 0) * B_];
            const float v1 = src[(kq * 4 + 1) * B_];
            const float v2 = src[(kq * 4 + 2) * B_];
            const float v3 = src[(kq * 4 + 3) * B_];
            const int k4 = ksub * 32 + kq;
            #pragma unroll
            for (int c = 0; c < 8; ++c) {
                const float4 w = ((const float4*)(&Wlds[c][0]))[k4];
                acc[c] += v0 * w.x + v1 * w.y + v2 * w.z + v3 * w.w;
            }
        }
        #pragma unroll
        for (int c = 0; c < 8; ++c) parts[ksub][b][c] = acc[c];
        __syncthreads();

        if (tid < 256) {
            const int bb = tid >> 1, j = tid & 1;
            float z[4];
            #pragma unroll
            for (int g = 0; g < 4; ++g) {
                float s = bias_l[g*2 + j];
                #pragma unroll
                for (int ks = 0; ks < 8; ++ks) s += parts[ks][bb][g*2 + j];
                z[g] = s;
            }
            const float ut    = ut_lds[bb];
            const float ug    = rintf(ut);
            const float c_old = c_state[bb][j];
            const float si = sigm(z[0]);
            const float sf = sigm(z[1]);
            const float gg = tanhf(z[2]);
            const float so = sigm(z[3]);
            const float c_n = sf * c_old + si * gg;
            const float h_n = so * tanhf(c_n);
            const float h_old = hcurT[(u0 + j) * B_ + bb];
            const float hbv = ug * h_old + (1.f - ug) * h_n;
            const float cbv = ug * c_old + (1.f - ug) * c_n;
            out[(size_t)bb * (T_ * U_) + (size_t)t * U_ + u0 + j] = h_n;
            hnxtT[(u0 + j) * B_ + bb] = hbv;
            c_state[bb][j] = cbv;
            float p = hbv * dk_l[j] + cbv * dk_l[2 + j];
            p += __shfl_xor(p, 1);
            if (j == 0) pd[(t & 1) * (NBLK * B_) + blockIdx.x * B_ + bb] = p;
        }

        grid.sync();

        {
            const int bb2 = tid >> 3, o = tid & 7;
            const float* __restrict__ pdt = pd + (t & 1) * (NBLK * B_);
            float s = 0.f;
            #pragma unroll 1
            for (int i = 0; i < 32; ++i) s += pdt[(o * 32 + i) * B_ + bb2];
            s += __shfl_xor(s, 1);
            s += __shfl_xor(s, 2);
            s += __shfl_xor(s, 4);
            if (o == 0) {
                const float delta = sigm(s + db_l);
                const float ut = ut_lds[bb2];
                const float ug = rintf(ut);
                ut_lds[bb2] = ug * delta + (1.f - ug) * (ut + fminf(delta, 1.f - ut));
            }
        }
        __syncthreads();
    }
}

// ---------------- host -------------------------------------------------------------
extern "C" void kernel_launch(void* const* d_in, const int* in_sizes, int n_in,
                              void* d_out, int out_size, void* d_ws, size_t ws_size,
                              hipStream_t stream)
{
    (void)in_sizes; (void)n_in; (void)out_size;
    const float* x  = (const float*)d_in[0];
    const float* wk = (const float*)d_in[1];
    const float* wr = (const float*)d_in[2];
    const float* bs = (const float*)d_in[3];
    const float* dk = (const float*)d_in[4];
    const float* db = (const float*)d_in[5];
    float* out = (float*)d_out;

    const size_t xT_b   = (size_t)T_ * D_ * B_ * 4;          // 256 MiB
    const size_t wpk_b  = (size_t)NBLK * 1024 * 8 * 4;       // 8 MiB
    const size_t hbuf_b = (size_t)2 * U_ * B_ * 4;           // 512 KiB
    const size_t pd_b   = (size_t)2 * NBLK * B_ * 4;         // 256 KiB
    const size_t ctrl_b = 4096;
    const size_t zx32_b = (size_t)T_ * G4 * B_ * 4;          // 1 GiB
    const size_t zx16_b = zx32_b / 2;
    const size_t tail_b = hbuf_b + pd_b + ctrl_b;

    const size_t need_A = zx32_b + xT_b + wpk_b + tail_b;
    const size_t need_B = zx16_b + xT_b + wpk_b + tail_b;

    char* w = (char*)d_ws;

    if (ws_size >= need_B) {
        const bool f32zx = (ws_size >= need_A);
        const size_t zx_b = f32zx ? zx32_b : zx16_b;
        char* zxp  = w;
        float* xT  = (float*)(w + zx_b);
        float* Wpk = (float*)(w + zx_b + xT_b);
        float* hbuf = (float*)(w + zx_b + xT_b + wpk_b);
        float* pd   = (float*)(w + zx_b + xT_b + wpk_b + hbuf_b);
        unsigned* ctrl = (unsigned*)(w + zx_b + xT_b + wpk_b + hbuf_b + pd_b);

        hipMemsetAsync(hbuf, 0, tail_b, stream);
        transpose_x<<<dim3(T_ * 16 * 4), dim3(256), 0, stream>>>(x, xT);
        pack_w<<<dim3(2048), dim3(1024), 0, stream>>>(wk, wr, Wpk);

        if (f32zx) {
            float* zx = (float*)zxp;
            zx_gemm<float><<<dim3(NBLK), dim3(NTHR), 0, stream>>>(xT, Wpk, bs, zx);
            void* args[] = { (void*)&zx, (void*)&Wpk, (void*)&dk, (void*)&db,
                             (void*)&out, (void*)&hbuf, (void*)&pd, (void*)&ctrl };
            hipLaunchCooperativeKernel(reinterpret_cast<void*>(skiplstm_loop<float>),
                                       dim3(NBLK), dim3(NTHR), args, 0, stream);
        } else {
            __half* zx = (__half*)zxp;
            zx_gemm<__half><<<dim3(NBLK), dim3(NTHR), 0, stream>>>(xT, Wpk, bs, zx);
            void* args[] = { (void*)&zx, (void*)&Wpk, (void*)&dk, (void*)&db,
                             (void*)&out, (void*)&hbuf, (void*)&pd, (void*)&ctrl };
            hipLaunchCooperativeKernel(reinterpret_cast<void*>(skiplstm_loop<__half>),
                                       dim3(NBLK), dim3(NTHR), args, 0, stream);
        }
    } else {
        float* xT   = (float*)d_ws;
        float* hbuf = xT + (size_t)T_ * D_ * B_;
        float* pd   = hbuf + 2 * U_ * B_;
        transpose_x<<<dim3(T_ * 16 * 4), dim3(256), 0, stream>>>(x, xT);
        void* args[] = { (void*)&xT, (void*)&wk, (void*)&wr, (void*)&bs, (void*)&dk, (void*)&db,
                         (void*)&out, (void*)&hbuf, (void*)&pd };
        hipLaunchCooperativeKernel(reinterpret_cast<void*>(skiplstm_kernel_T),
                                   dim3(NBLK), dim3(NTHR), args, 0, stream);
    }
}

// Round 5
// 24717.239 us; speedup vs baseline: 1.1721x; 1.1721x over previous
//
#include <hip/hip_runtime.h>
#include <hip/hip_fp16.h>
#include <hip/hip_cooperative_groups.h>

namespace cg = cooperative_groups;

constexpr int B_ = 128, T_ = 1024, D_ = 512, U_ = 512;
constexpr int NBLK = 256, NTHR = 1024;
constexpr int G4 = 4 * U_;     // 2048 gate columns
// loop2 geometry: 2 row-groups x 128 blocks; block = 64 rows x 16 gate cols (4 u)
constexpr int RGN = 2, RBLK = 128, RROWS = 64, UPB = 4;

__device__ __forceinline__ float sigm(float v) { return 1.0f / (1.0f + expf(-v)); }

#define AGENT_LD(p)    __hip_atomic_load((p), __ATOMIC_RELAXED, __HIP_MEMORY_SCOPE_AGENT)
#define AGENT_ST(p, v) __hip_atomic_store((p), (v), __ATOMIC_RELAXED, __HIP_MEMORY_SCOPE_AGENT)

template <typename ZT> __device__ __forceinline__ ZT    to_zt(float v);
template <> __device__ __forceinline__ float  to_zt<float>(float v)  { return v; }
template <> __device__ __forceinline__ __half to_zt<__half>(float v) { return __float2half(v); }
__device__ __forceinline__ float from_zt(float v)  { return v; }
__device__ __forceinline__ float from_zt(__half v) { return __half2float(v); }

// ---------------- x[b][t][k] -> xT[t][k][b] ----------------------------------------
__global__ __launch_bounds__(256) void transpose_x(const float* __restrict__ x,
                                                   float* __restrict__ xT)
{
    __shared__ float tile[32][33];
    const int tileId = blockIdx.x;
    const int bt = tileId & 3;
    const int kt = (tileId >> 2) & 15;
    const int t  = tileId >> 6;
    const int tx = threadIdx.x & 31;
    const int ty = threadIdx.x >> 5;
    #pragma unroll
    for (int r = 0; r < 4; ++r) {
        const int b = bt * 32 + ty + r * 8;
        const int k = kt * 32 + tx;
        tile[ty + r * 8][tx] = x[(size_t)b * (T_ * D_) + (size_t)t * D_ + k];
    }
    __syncthreads();
    #pragma unroll
    for (int r = 0; r < 4; ++r) {
        const int k = kt * 32 + ty + r * 8;
        const int b = bt * 32 + tx;
        xT[((size_t)t * D_ + k) * B_ + b] = tile[tx][ty + r * 8];
    }
}

// ---------------- pack W (for zx_gemm): Wpk[blk256][k1024][c8] ---------------------
__global__ __launch_bounds__(1024) void pack_w(const float* __restrict__ wk,
                                               const float* __restrict__ wr,
                                               float* __restrict__ Wpk)
{
    const size_t idx = (size_t)blockIdx.x * 1024 + threadIdx.x;
    const int    c   = (int)(idx & 7);
    const size_t k   = (idx >> 3) & 1023;
    const int    blk = (int)(idx >> 13);
    const int    col = ((c >> 1) << 9) + blk * 2 + (c & 1);
    Wpk[idx] = (k < 512) ? wk[k * G4 + col] : wr[(k - 512) * G4 + col];
}

// ---------------- pack W_r (for loop2): Wpk2[ub128][k512][c16], c = g*4+u ----------
__global__ __launch_bounds__(1024) void pack_w2(const float* __restrict__ wr,
                                                float* __restrict__ Wpk2)
{
    const size_t idx = (size_t)blockIdx.x * 1024 + threadIdx.x;  // 1,048,576 total
    const int c  = (int)(idx & 15);
    const int k  = (int)((idx >> 4) & 511);
    const int ub = (int)(idx >> 13);
    const int g = c >> 2, u = c & 3;
    Wpk2[idx] = wr[(size_t)k * G4 + g * 512 + ub * 4 + u];
}

// ---------------- zx[t][gc][b] = bias + x_t @ Wk  (proven R3 kernel) ---------------
template <typename ZT>
__global__ __launch_bounds__(NTHR, 4) void zx_gemm(
    const float* __restrict__ xT, const float* __restrict__ Wpk,
    const float* __restrict__ bias, ZT* __restrict__ zx)
{
    __shared__ float parts[8][128][9];
    __shared__ float bias_l[8];
    const int tid = threadIdx.x, blk = blockIdx.x, u0 = blk * 2;
    if (tid < 8) bias_l[tid] = bias[(tid >> 1) * U_ + u0 + (tid & 1)];
    const int b = tid & 127, ksub = tid >> 7;
    const int ksub_u = __builtin_amdgcn_readfirstlane(ksub);
    const float* __restrict__ wp = Wpk + ((size_t)blk * 1024 + (size_t)ksub_u * 64) * 8;
    __syncthreads();

    for (int t = 0; t < T_; ++t) {
        const float* __restrict__ xp = xT + ((size_t)t * D_ + ksub * 64) * B_ + b;
        float acc[8] = {0.f,0.f,0.f,0.f,0.f,0.f,0.f,0.f};
        #pragma unroll 2
        for (int kq = 0; kq < 16; ++kq) {
            const float v0 = xp[(kq * 4 + 0) * B_];
            const float v1 = xp[(kq * 4 + 1) * B_];
            const float v2 = xp[(kq * 4 + 2) * B_];
            const float v3 = xp[(kq * 4 + 3) * B_];
            const float* __restrict__ w = wp + kq * 32;
            #pragma unroll
            for (int c = 0; c < 8; ++c)
                acc[c] += v0 * w[c] + v1 * w[8 + c] + v2 * w[16 + c] + v3 * w[24 + c];
        }
        #pragma unroll
        for (int c = 0; c < 8; ++c) parts[ksub][b][c] = acc[c];
        __syncthreads();
        {
            const int c = tid >> 7, bb = tid & 127;
            float s = bias_l[c];
            #pragma unroll
            for (int ks = 0; ks < 8; ++ks) s += parts[ks][bb][c];
            zx[((size_t)t * G4 + (c >> 1) * U_ + u0 + (c & 1)) * B_ + bb] = to_zt<ZT>(s);
        }
        __syncthreads();
    }
}

// ---------------- main recurrent loop: row-group split -----------------------------
// blk: rg = blk>>7 (row group, 64 rows), ub = blk&127 (4 u's -> 16 gate cols).
// thread: row = tid&63, kg = tid>>6 (16 kgroups of K=32). Wave = 1 kg x 64 rows
// -> W via s_load_dwordx16; h loads 256B coalesced. Barrier per row group
// (hierarchical 8 groups x 16). Delta reduced redundantly per block.
// ctrl (uints): per rg at rg*256: [g*16] group ctr (g<8), [128] root.
template <typename ZT>
__global__ __launch_bounds__(NTHR, 4) void skiplstm_loop2(
    const ZT* __restrict__ zx, const float* __restrict__ Wpk2,
    const float* __restrict__ dk, const float* __restrict__ dbp,
    float* __restrict__ out, float* __restrict__ hbuf,
    float* __restrict__ pd, unsigned* __restrict__ ctrl)
{
    __shared__ float parts[16][64][17];   // [kg][row][col] pad 17 -> conflict-free
    __shared__ float zxl[16][64];
    __shared__ float red[16][66];
    __shared__ float pdp[4][64];
    __shared__ float c_state[64][4];
    __shared__ float h_state[64][4];
    __shared__ float ut_lds[64];
    __shared__ float dk_l[8];
    __shared__ float db_l;

    const int tid = threadIdx.x;
    const int blk = blockIdx.x;
    const int rg  = blk >> 7;
    const int ub  = blk & 127;
    const int rowbase = rg * RROWS;

    if (tid < 4) { dk_l[tid] = dk[ub * 4 + tid]; dk_l[4 + tid] = dk[U_ + ub * 4 + tid]; }
    if (tid == 0) db_l = dbp[0];
    if (tid < 64) {
        ut_lds[tid] = 1.0f;
        #pragma unroll
        for (int u = 0; u < 4; ++u) { c_state[tid][u] = 0.f; h_state[tid][u] = 0.f; }
    }
    __syncthreads();

    const int row = tid & 63;
    const int kg  = tid >> 6;
    const int kg_u = __builtin_amdgcn_readfirstlane(kg);
    const float* __restrict__ wp = Wpk2 + ((size_t)ub * 512 + (size_t)kg_u * 32) * 16;

    unsigned* __restrict__ grp  = ctrl + rg * 256 + (ub >> 4) * 16;
    unsigned* __restrict__ root = ctrl + rg * 256 + 128;

    #pragma unroll 1
    for (int t = 0; t < T_; ++t) {
        const float* __restrict__ hcur = hbuf + (t & 1) * (U_ * B_);
        float* __restrict__ hnxt = hbuf + ((t + 1) & 1) * (U_ * B_);

        // [A] zx prefetch (issued early; consumed after [C])
        const int zc = kg;                       // 16 cols, one per kg
        const ZT zv = zx[((size_t)t * G4 + (zc >> 2) * U_ + ub * 4 + (zc & 3)) * B_
                         + rowbase + row];

        // [B] h @ Wr : K-range 32 per thread, 16 cols
        const float* __restrict__ hp = hcur + rowbase + row;
        const int k0 = kg * 32;
        float acc[16];
        #pragma unroll
        for (int c = 0; c < 16; ++c) acc[c] = 0.f;
        #pragma unroll
        for (int ii = 0; ii < 4; ++ii) {
            float hv[8];
            #pragma unroll
            for (int j = 0; j < 8; ++j)
                hv[j] = AGENT_LD(hp + (size_t)(k0 + ii * 8 + j) * B_);
            #pragma unroll
            for (int j = 0; j < 8; ++j) {
                const float* __restrict__ w = wp + (ii * 8 + j) * 16;  // s_load x16
                #pragma unroll
                for (int c = 0; c < 16; ++c) acc[c] += hv[j] * w[c];
            }
        }
        #pragma unroll
        for (int c = 0; c < 16; ++c) parts[kg][row][c] = acc[c];
        zxl[zc][row] = from_zt(zv);
        __syncthreads();   // [C]

        // [F] gates/blend/output (waves 0-3: 64 rows x 4 u)
        if (tid < 256) {
            const int u = tid >> 6, r = tid & 63;
            float z[4];
            #pragma unroll
            for (int g = 0; g < 4; ++g) {
                float s = zxl[g * 4 + u][r];
                #pragma unroll
                for (int kk = 0; kk < 16; ++kk) s += parts[kk][r][g * 4 + u];
                z[g] = s;
            }
            const float ut = ut_lds[r];
            const float ug = rintf(ut);
            const float c_old = c_state[r][u];
            const float si = sigm(z[0]);
            const float sf = sigm(z[1]);
            const float gt = tanhf(z[2]);
            const float so = sigm(z[3]);
            const float c_n = sf * c_old + si * gt;
            const float h_n = so * tanhf(c_n);
            const float h_old = h_state[r][u];
            const float hbv = ug * h_old + (1.f - ug) * h_n;
            const float cbv = ug * c_old + (1.f - ug) * c_n;
            const int b = rowbase + r, uglob = ub * 4 + u;
            out[(size_t)b * (T_ * U_) + (size_t)t * U_ + uglob] = h_n;
            AGENT_ST(hnxt + (size_t)uglob * B_ + b, hbv);
            c_state[r][u] = cbv;
            h_state[r][u] = hbv;
            pdp[u][r] = hbv * dk_l[u] + cbv * dk_l[4 + u];
        }
        __syncthreads();
        if (tid < 64) {
            const float p = pdp[0][tid] + pdp[1][tid] + pdp[2][tid] + pdp[3][tid];
            AGENT_ST(pd + (t & 1) * (RGN * RBLK * RROWS) + rg * (RBLK * RROWS)
                        + ub * RROWS + tid, p);
        }
        __syncthreads();   // [G] drain stores before arrive

        if (t < T_ - 1) {
            // [H1] hierarchical row-group barrier (single-thread arrive + poll)
            if (tid == 0) {
                const unsigned old = __hip_atomic_fetch_add(grp, 1u,
                                        __ATOMIC_RELEASE, __HIP_MEMORY_SCOPE_AGENT);
                if (old + 1u == (unsigned)(16 * (t + 1)))
                    __hip_atomic_fetch_add(root, 1u,
                                        __ATOMIC_RELEASE, __HIP_MEMORY_SCOPE_AGENT);
                const unsigned tgt = (unsigned)(8 * (t + 1));
                while (__hip_atomic_load(root, __ATOMIC_RELAXED,
                                         __HIP_MEMORY_SCOPE_AGENT) < tgt)
                    __builtin_amdgcn_s_sleep(2);
            }
            __syncthreads();

            // [H2] redundant delta reduce for this row group (coalesced)
            {
                const float* __restrict__ pdt =
                    pd + (t & 1) * (RGN * RBLK * RROWS) + rg * (RBLK * RROWS);
                const int i = tid >> 6, r2 = tid & 63;
                float s = 0.f;
                #pragma unroll
                for (int j = 0; j < 8; ++j)
                    s += AGENT_LD(pdt + (size_t)(i * 8 + j) * RROWS + r2);
                red[i][r2] = s;
            }
            __syncthreads();
            if (tid < 64) {
                float ss = 0.f;
                #pragma unroll
                for (int i2 = 0; i2 < 16; ++i2) ss += red[i2][tid];
                const float dlt = sigm(ss + db_l);
                const float utv = ut_lds[tid];
                const float ugv = rintf(utv);
                ut_lds[tid] = ugv * dlt + (1.f - ugv) * (utv + fminf(dlt, 1.f - utv));
            }
            // next read of ut_lds is in [F](t+1), after [C](t+1) sync -> safe
        }
    }
}

// ---------------- R2 fallback (ws too small): proven 55 ms path --------------------
__global__ __launch_bounds__(NTHR, 4) void skiplstm_kernel_T(
    const float* __restrict__ xT, const float* __restrict__ wk,
    const float* __restrict__ wr, const float* __restrict__ bias,
    const float* __restrict__ dk, const float* __restrict__ dbp,
    float* __restrict__ out, float* __restrict__ hbuf, float* __restrict__ pd)
{
    __shared__ __align__(16) float Wlds[8][1024];
    __shared__ float parts[8][128][9];
    __shared__ float c_state[128][2];
    __shared__ float ut_lds[128];
    __shared__ float bias_l[8];
    __shared__ float dk_l[4];
    __shared__ float db_l;

    const int tid = threadIdx.x;
    const int u0 = blockIdx.x * 2;

    #pragma unroll
    for (int c = 0; c < 8; ++c) {
        const int g = c >> 1, j = c & 1;
        const int gcol = g * U_ + u0 + j;
        Wlds[c][tid] = (tid < D_) ? wk[(size_t)tid * G4 + gcol]
                                  : wr[(size_t)(tid - D_) * G4 + gcol];
    }
    if (tid < 8)  bias_l[tid] = bias[(tid >> 1) * U_ + u0 + (tid & 1)];
    if (tid < 2) { dk_l[tid] = dk[u0 + tid]; dk_l[2 + tid] = dk[U_ + u0 + tid]; }
    if (tid == 0) db_l = dbp[0];
    if (tid < 128) { ut_lds[tid] = 1.0f; c_state[tid][0] = 0.0f; c_state[tid][1] = 0.0f; }
    if (tid < 512) hbuf[blockIdx.x * 512 + tid] = 0.0f;

    cg::grid_group grid = cg::this_grid();
    __syncthreads();
    grid.sync();

    const int b    = tid & 127;
    const int ksub = tid >> 7;

    #pragma unroll 1
    for (int t = 0; t < T_; ++t) {
        const float* __restrict__ hcurT = hbuf + (t & 1) * (U_ * B_);
        float* __restrict__ hnxtT = hbuf + ((t + 1) & 1) * (U_ * B_);

        const float* __restrict__ src = (ksub < 4)
            ? (xT + ((size_t)t * D_ + ksub * 128) * B_ + b)
            : (hcurT + (size_t)(ksub - 4) * 128 * B_ + b);

        float acc[8] = {0.f,0.f,0.f,0.f,0.f,0.f,0.f,0.f};
        #pragma unroll 2
        for (int kq = 0; kq < 32; ++kq) {
            const float v0 = src[(kq * 4 + 0) * B_];
            const float v1 = src[(kq * 4 + 1) * B_];
            const float v2 = src[(kq * 4 + 2) * B_];
            const float v3 = src[(kq * 4 + 3) * B_];
            const int k4 = ksub * 32 + kq;
            #pragma unroll
            for (int c = 0; c < 8; ++c) {
                const float4 w = ((const float4*)(&Wlds[c][0]))[k4];
                acc[c] += v0 * w.x + v1 * w.y + v2 * w.z + v3 * w.w;
            }
        }
        #pragma unroll
        for (int c = 0; c < 8; ++c) parts[ksub][b][c] = acc[c];
        __syncthreads();

        if (tid < 256) {
            const int bb = tid >> 1, j = tid & 1;
            float z[4];
            #pragma unroll
            for (int g = 0; g < 4; ++g) {
                float s = bias_l[g*2 + j];
                #pragma unroll
                for (int ks = 0; ks < 8; ++ks) s += parts[ks][bb][g*2 + j];
                z[g] = s;
            }
            const float ut    = ut_lds[bb];
            const float ug    = rintf(ut);
            const float c_old = c_state[bb][j];
            const float si = sigm(z[0]);
            const float sf = sigm(z[1]);
            const float gg = tanhf(z[2]);
            const float so = sigm(z[3]);
            const float c_n = sf * c_old + si * gg;
            const float h_n = so * tanhf(c_n);
            const float h_old = hcurT[(u0 + j) * B_ + bb];
            const float hbv = ug * h_old + (1.f - ug) * h_n;
            const float cbv = ug * c_old + (1.f - ug) * c_n;
            out[(size_t)bb * (T_ * U_) + (size_t)t * U_ + u0 + j] = h_n;
            hnxtT[(u0 + j) * B_ + bb] = hbv;
            c_state[bb][j] = cbv;
            float p = hbv * dk_l[j] + cbv * dk_l[2 + j];
            p += __shfl_xor(p, 1);
            if (j == 0) pd[(t & 1) * (NBLK * B_) + blockIdx.x * B_ + bb] = p;
        }

        grid.sync();

        {
            const int bb2 = tid >> 3, o = tid & 7;
            const float* __restrict__ pdt = pd + (t & 1) * (NBLK * B_);
            float s = 0.f;
            #pragma unroll 1
            for (int i = 0; i < 32; ++i) s += pdt[(o * 32 + i) * B_ + bb2];
            s += __shfl_xor(s, 1);
            s += __shfl_xor(s, 2);
            s += __shfl_xor(s, 4);
            if (o == 0) {
                const float delta = sigm(s + db_l);
                const float ut = ut_lds[bb2];
                const float ug = rintf(ut);
                ut_lds[bb2] = ug * delta + (1.f - ug) * (ut + fminf(delta, 1.f - ut));
            }
        }
        __syncthreads();
    }
}

// ---------------- host -------------------------------------------------------------
extern "C" void kernel_launch(void* const* d_in, const int* in_sizes, int n_in,
                              void* d_out, int out_size, void* d_ws, size_t ws_size,
                              hipStream_t stream)
{
    (void)in_sizes; (void)n_in; (void)out_size;
    const float* x  = (const float*)d_in[0];
    const float* wk = (const float*)d_in[1];
    const float* wr = (const float*)d_in[2];
    const float* bs = (const float*)d_in[3];
    const float* dk = (const float*)d_in[4];
    const float* db = (const float*)d_in[5];
    float* out = (float*)d_out;

    const size_t xT_b   = (size_t)T_ * D_ * B_ * 4;            // 256 MiB
    const size_t wpk_b  = (size_t)NBLK * 1024 * 8 * 4;         // 8 MiB
    const size_t wpk2_b = (size_t)RBLK * 512 * 16 * 4;         // 4 MiB
    const size_t hbuf_b = (size_t)2 * U_ * B_ * 4;             // 512 KiB
    const size_t pd_b   = (size_t)2 * RGN * RBLK * RROWS * 4;  // 128 KiB
    const size_t ctrl_b = 4096;
    const size_t zx32_b = (size_t)T_ * G4 * B_ * 4;            // 1 GiB
    const size_t zx16_b = zx32_b / 2;
    const size_t tail_b = hbuf_b + pd_b + ctrl_b;

    const size_t need_A = zx32_b + xT_b + wpk_b + wpk2_b + tail_b;
    const size_t need_B = zx16_b + xT_b + wpk_b + wpk2_b + tail_b;

    char* w = (char*)d_ws;

    if (ws_size >= need_B) {
        const bool f32zx = (ws_size >= need_A);
        const size_t zx_b = f32zx ? zx32_b : zx16_b;
        char*  zxp  = w;
        float* xT   = (float*)(w + zx_b);
        float* Wpk  = (float*)(w + zx_b + xT_b);
        float* Wpk2 = (float*)(w + zx_b + xT_b + wpk_b);
        float* hbuf = (float*)(w + zx_b + xT_b + wpk_b + wpk2_b);
        float* pd   = (float*)(w + zx_b + xT_b + wpk_b + wpk2_b + hbuf_b);
        unsigned* ctrl = (unsigned*)(w + zx_b + xT_b + wpk_b + wpk2_b + hbuf_b + pd_b);

        hipMemsetAsync(hbuf, 0, tail_b, stream);
        transpose_x<<<dim3(T_ * 16 * 4), dim3(256), 0, stream>>>(x, xT);
        pack_w<<<dim3(2048), dim3(1024), 0, stream>>>(wk, wr, Wpk);
        pack_w2<<<dim3(1024), dim3(1024), 0, stream>>>(wr, Wpk2);

        if (f32zx) {
            float* zx = (float*)zxp;
            zx_gemm<float><<<dim3(NBLK), dim3(NTHR), 0, stream>>>(xT, Wpk, bs, zx);
            void* args[] = { (void*)&zx, (void*)&Wpk2, (void*)&dk, (void*)&db,
                             (void*)&out, (void*)&hbuf, (void*)&pd, (void*)&ctrl };
            hipLaunchCooperativeKernel(reinterpret_cast<void*>(skiplstm_loop2<float>),
                                       dim3(NBLK), dim3(NTHR), args, 0, stream);
        } else {
            __half* zx = (__half*)zxp;
            zx_gemm<__half><<<dim3(NBLK), dim3(NTHR), 0, stream>>>(xT, Wpk, bs, zx);
            void* args[] = { (void*)&zx, (void*)&Wpk2, (void*)&dk, (void*)&db,
                             (void*)&out, (void*)&hbuf, (void*)&pd, (void*)&ctrl };
            hipLaunchCooperativeKernel(reinterpret_cast<void*>(skiplstm_loop2<__half>),
                                       dim3(NBLK), dim3(NTHR), args, 0, stream);
        }
    } else {
        float* xT   = (float*)d_ws;
        float* hbuf = xT + (size_t)T_ * D_ * B_;
        float* pd   = hbuf + 2 * U_ * B_;
        transpose_x<<<dim3(T_ * 16 * 4), dim3(256), 0, stream>>>(x, xT);
        void* args[] = { (void*)&xT, (void*)&wk, (void*)&wr, (void*)&bs, (void*)&dk, (void*)&db,
                         (void*)&out, (void*)&hbuf, (void*)&pd };
        hipLaunchCooperativeKernel(reinterpret_cast<void*>(skiplstm_kernel_T),
                                   dim3(NBLK), dim3(NTHR), args, 0, stream);
    }
}